// Round 13
// baseline (335.398 us; speedup 1.0000x reference)
//
#include <hip/hip_runtime.h>
#include <cstdint>

#define B_IMG   8
#define NCAND   36720
#define PD      85
#define NCLS    80
#define KC      512
#define MAXDET  300
#define NBUCK   2048
#define CANDCAP 1024      // gathered count is ~512 + one-bucket (<~40): 1024 is safe

// G (fp32, level-major) float offsets: L1[8][9216][64] | L2[8][2304][64] | L3[8][576][64] | L4[8][144][64]
#define G2_OFF 4718592
#define G3_OFF 5898240
#define G4_OFF 6193152
#define G_TOT  6266880

// Partial-sum buffer P (float offsets within P)
#define P2_BASE 0
#define P2_SLAB 1179648
#define P3_BASE 2359296
#define P3_SLAB 294912
#define P4_BASE 3538944
#define P4_SLAB 73728

typedef unsigned int u32;
typedef unsigned long long u64;

__device__ __forceinline__ float leaky(float x){ return x >= 0.f ? x : 0.01f*x; }

__device__ __forceinline__ u64 shfl_u64(u64 v, int lane){
  int lo = __shfl((int)(u32)(v & 0xFFFFFFFFull), lane, 64);
  int hi = __shfl((int)(u32)(v >> 32), lane, 64);
  return ((u64)(u32)hi << 32) | (u64)(u32)lo;
}
__device__ __forceinline__ u64 shfl_xor_u64(u64 v, int mask){
  int lo = __shfl_xor((int)(u32)(v & 0xFFFFFFFFull), mask, 64);
  int hi = __shfl_xor((int)(u32)(v >> 32), mask, 64);
  return ((u64)(u32)hi << 32) | (u64)(u32)lo;
}

__device__ __forceinline__ void gld16(const void* g, void* l){
  __builtin_amdgcn_global_load_lds((const __attribute__((address_space(1))) void*)g,
                                   (__attribute__((address_space(3))) void*)l, 16, 0, 0);
}

// ================= proj work (R7 config: 128 thr, 16-ch chunks, 24KB LDS) =====
// R16: R8's 256-thr/8-ch proj retile REGRESSED (~+30us: 2x barriers, 3 loads
// in flight vs 6); R7's config measured < 58.6us. Keep R7 proj VERBATIM as a
// device function; pipeline it under the NMS chain by block-slicing the 144
// works/img across two fused kernels (even works with score, odd with
// gather). No new partials, same stores, same c-ascending order ->
// bit-identical output.
__device__ __forceinline__ void stage_chunk(const float4* __restrict__ feat4,
    const float4* __restrict__ W14, long fbase, int hw4, int px04, int Woff,
    int c0, int tid, float4* FsD, float4* WsD){
  const int wb = tid & ~63;                      // wave-uniform LDS base
  #pragma unroll
  for (int k = 0; k < 4; k++){                   // Fs: 16c x 32 f4 = 512 slots
    int s = tid + k*128; int c = s >> 5, q = s & 31;
    int pq = px04 + q; if (pq >= hw4) pq = hw4 - 1;   // ragged tile clamp (stores guarded)
    gld16(feat4 + fbase + (long)(c0 + c)*hw4 + pq, FsD + k*128 + wb);
  }
  #pragma unroll
  for (int k = 0; k < 2; k++){                   // Ws: 16c x 16 f4 = 256 slots
    int s = tid + k*128; int c = s >> 4, q = s & 15;
    gld16(W14 + (long)(Woff + c0 + c)*16 + q, WsD + k*128 + wb);
  }
}

#define FMA_Q(S, W, A) \
  A.x = fmaf(S, W.x, A.x); A.y = fmaf(S, W.y, A.y); \
  A.z = fmaf(S, W.z, A.z); A.w = fmaf(S, W.w, A.w);

__device__ __forceinline__ void proj_work(int w, int img, int tid,
    const float* __restrict__ f1, const float* __restrict__ f2,
    const float* __restrict__ f3, const float* __restrict__ f4,
    const float* __restrict__ W1, float* __restrict__ G, float* __restrict__ P,
    float* smem){
  float4* Fs0 = (float4*)smem;            // 512 f4 (16c x 32)
  float4* Fs1 = Fs0 + 512;
  float4* Ws0 = Fs0 + 1024;               // 256 f4 (16c x 16)
  float4* Ws1 = Fs0 + 1280;               // total 1536 f4 = 24 KB
  const float* feat; int C, HW, Woff, tile, split; long pbase; bool multi;
  if (w < 16)      { feat=f4; C=1024; HW=144;  Woff=896; tile=w>>3;      split=w&7;
                     pbase=P4_BASE + (long)split*P4_SLAB; multi=true;  }
  else if (w < 36) { feat=f3; C=512;  HW=576;  Woff=384; tile=(w-16)>>2; split=(w-16)&3;
                     pbase=P3_BASE + (long)split*P3_SLAB; multi=true;  }
  else if (w < 72) { feat=f2; C=256;  HW=2304; Woff=128; tile=(w-36)>>1; split=(w-36)&1;
                     pbase=P2_BASE + (long)split*P2_SLAB; multi=true;  }
  else             { feat=f1; C=128;  HW=9216; Woff=0;   tile=w-72;      split=0;
                     pbase=0; multi=false; }
  const int px0  = tile*128;
  const int hw4  = HW >> 2;
  const int px04 = px0 >> 2;
  const int jg   = tid & 7;         // j = jg*8 + jj (lane-fast axis)
  const int pg   = tid >> 3;        // px = px0 + pg*8 + p, pg=0..15
  const int c0b  = split*128;
  const float4* feat4 = (const float4*)feat;
  const float4* W14   = (const float4*)W1;
  const long fbase = (long)img*C*hw4;
  float4 z = make_float4(0.f,0.f,0.f,0.f);
  float4 aA0=z,aA1=z,aA2=z,aA3=z,aA4=z,aA5=z,aA6=z,aA7=z;  // j jg*8..+3
  float4 aB0=z,aB1=z,aB2=z,aB3=z,aB4=z,aB5=z,aB6=z,aB7=z;  // j jg*8+4..+7

  stage_chunk(feat4, W14, fbase, hw4, px04, Woff, c0b, tid, Fs0, Ws0);
  __syncthreads();                               // drains vmcnt: buf0 ready
  for (int ch = 0; ch < 8; ch++){
    if (ch < 7)                                  // issue next chunk into buf^1
      stage_chunk(feat4, W14, fbase, hw4, px04, Woff, c0b + (ch+1)*16, tid,
                  (ch & 1) ? Fs0 : Fs1, (ch & 1) ? Ws0 : Ws1);
    const float4* fsb = (ch & 1) ? Fs1 : Fs0;
    const float4* wsb = (ch & 1) ? Ws1 : Ws0;
    #pragma unroll 4
    for (int c = 0; c < 16; c++){
      float4 fa = fsb[c*32 + pg*2];        // px p=0..3   (8-lane broadcast)
      float4 fb = fsb[c*32 + pg*2 + 1];    // px p=4..7
      float4 wa = wsb[c*16 + jg*2];        // j jj=0..3   (2-way aliased: free)
      float4 wc = wsb[c*16 + jg*2 + 1];    // j jj=4..7
      FMA_Q(fa.x, wa, aA0) FMA_Q(fa.y, wa, aA1) FMA_Q(fa.z, wa, aA2) FMA_Q(fa.w, wa, aA3)
      FMA_Q(fb.x, wa, aA4) FMA_Q(fb.y, wa, aA5) FMA_Q(fb.z, wa, aA6) FMA_Q(fb.w, wa, aA7)
      FMA_Q(fa.x, wc, aB0) FMA_Q(fa.y, wc, aB1) FMA_Q(fa.z, wc, aB2) FMA_Q(fa.w, wc, aB3)
      FMA_Q(fb.x, wc, aB4) FMA_Q(fb.y, wc, aB5) FMA_Q(fb.z, wc, aB6) FMA_Q(fb.w, wc, aB7)
    }
    __syncthreads();                             // next-chunk loads drained + compute done
  }
  float* outb = multi ? (P + pbase + (long)img*HW*64)
                      : (G + (long)img*HW*64);           // L1 region starts at G+0
  const int pxa = px0 + pg*8;
#define STOREQ(A, B, PP) do { int gp = pxa + (PP); if (gp < HW){ \
    *(float4*)(outb + (long)gp*64 + jg*8) = A; \
    *(float4*)(outb + (long)gp*64 + jg*8 + 4) = B; } } while(0)
  STOREQ(aA0, aB0, 0); STOREQ(aA1, aB1, 1); STOREQ(aA2, aB2, 2); STOREQ(aA3, aB3, 3);
  STOREQ(aA4, aB4, 4); STOREQ(aA5, aB5, 5); STOREQ(aA6, aB6, 6); STOREQ(aA7, aB7, 7);
#undef STOREQ
}

// ---------------- KA: fused score (blocks 0..287) + proj even works (288..359) ----
__global__ __launch_bounds__(128) void k_front_a(const float* __restrict__ preds,
    u32* __restrict__ sbits, int* __restrict__ clsArr, u32* __restrict__ hist,
    const float* __restrict__ f1, const float* __restrict__ f2,
    const float* __restrict__ f3, const float* __restrict__ f4,
    const float* __restrict__ W1, float* __restrict__ G, float* __restrict__ P){
  __shared__ __align__(16) float smem[6144];     // 24 KB union
  const int img = blockIdx.y;
  const int u   = blockIdx.x;
  const int tid = threadIdx.x;

  if (u < 288){
    // ---- score (2 waves/block) ----
    u32*   sl_lane = (u32*)smem;          // [2][64]
    float* sl_obj  = smem + 128;
    u32*   sl_res  = (u32*)(smem + 256);
    u32*   sl_cls  = (u32*)(smem + 384);
    const int wv   = tid >> 6;
    const int lane = tid & 63;
    const int base = (u*2 + wv)*64;
    const int ci   = base + lane;
    const bool inb = ci < NCAND;
    float obj = 0.f;
    if (inb) obj = preds[((long)img*NCAND + ci)*PD + 4];
    const bool pass = obj > 0.596f;
    u64 mask = __ballot(pass);
    int cnt  = __popcll(mask);
    int rank = __popcll(mask & ((1ull << lane) - 1ull));
    if (pass){ sl_lane[wv*64 + rank] = (u32)lane; sl_obj[wv*64 + rank] = obj; }
    const int q = lane & 3;
    for (int r0 = 0; r0 < cnt; r0 += 16){
      int idx = r0 + (lane >> 2);
      if (idx < cnt){
        u32 sl = sl_lane[wv*64 + idx];
        float obj2 = sl_obj[wv*64 + idx];
        const float* p2 = preds + ((long)img*NCAND + base + (int)sl)*PD + 5 + q;
        u64 best = 0ull;
        #pragma unroll
        for (int k = 0; k < 20; k++){
          float v = p2[4*k] * obj2;                       // exact ref: cls*obj
          u64 key = ((u64)__float_as_uint(v) << 32) | (u64)(~(u32)(q + 4*k));
          if (key > best) best = key;                     // first max wins
        }
        u64 o1 = shfl_xor_u64(best, 1); if (o1 > best) best = o1;
        u64 o2 = shfl_xor_u64(best, 2); if (o2 > best) best = o2;
        if (q == 0){
          u32 bits = (u32)(best >> 32);
          sl_res[wv*64 + sl] = (__uint_as_float(bits) > 0.596f) ? bits : 0u;
          sl_cls[wv*64 + sl] = ~(u32)(best & 0xFFFFFFFFull);
        }
      }
    }
    if (inb){
      u32 out = pass ? sl_res[wv*64 + lane] : 0u;
      sbits[(long)img*NCAND + ci] = out;
      if (pass) clsArr[(long)img*NCAND + ci] = (int)sl_cls[wv*64 + lane];
      if (out) atomicAdd(&hist[img*NBUCK + ((out - 0x3F000000u) >> 12)], 1u);
    }
    return;
  }
  proj_work((u - 288)*2, img, tid, f1, f2, f3, f4, W1, G, P, smem);
}

// ---------------- K2: per-image bit-threshold covering top-512 ----------------
__global__ __launch_bounds__(64) void k_thresh(const u32* __restrict__ hist,
                                               u32* __restrict__ thr){
  const int img = blockIdx.x;
  const int lane = threadIdx.x;
  const u32* h = hist + img*NBUCK;
  u32 acc = 0; u32 result = 0x3F000000u; bool found = false;
  for (int g = NBUCK/64 - 1; g >= 0 && !found; g--){
    u32 v = h[g*64 + lane];
    u32 s = v;
    #pragma unroll
    for (int off = 1; off < 64; off <<= 1){
      u32 t = __shfl_down(s, off, 64);
      s += (lane + off < 64) ? t : 0u;
    }
    u64 mask = __ballot(acc + s >= KC);
    if (mask){
      int hl = 63 - __clzll(mask);
      result = 0x3F000000u + ((u32)(g*64 + hl) << 12);
      found = true;
    }
    acc += __shfl(s, 0, 64);
  }
  if (lane == 0) thr[img] = result;
}

// ---------------- KB: fused gather (blocks 0..287) + proj odd works (288..359) ----
__global__ __launch_bounds__(128) void k_front_b(const u32* __restrict__ sbits,
    const u32* __restrict__ thr, u32* __restrict__ cnt, u64* __restrict__ cand,
    const float* __restrict__ f1, const float* __restrict__ f2,
    const float* __restrict__ f3, const float* __restrict__ f4,
    const float* __restrict__ W1, float* __restrict__ G, float* __restrict__ P){
  __shared__ __align__(16) float smem[6144];     // 24 KB (proj path only)
  const int img = blockIdx.y;
  const int u   = blockIdx.x;
  const int tid = threadIdx.x;
  if (u < 288){
    int n = u*128 + tid;
    if (n >= NCAND) return;
    u32 bits = sbits[(long)img*NCAND + n];
    if (bits && bits >= thr[img]){
      u32 pos = atomicAdd(&cnt[img], 1u);
      if (pos < CANDCAP)
        cand[(long)img*CANDCAP + pos] = ((u64)bits << 32) | (u64)(0xFFFFFFFFu - (u32)n);
    }
    return;
  }
  proj_work((u - 288)*2 + 1, img, tid, f1, f2, f3, f4, W1, G, P, smem);
}

// ---------------- K_MID: fused rank (blocks 0..31) + split-K reduce (32..1543) ----
__global__ __launch_bounds__(256) void k_mid(const float* __restrict__ preds,
    const int* __restrict__ clsArr, const u64* __restrict__ cand,
    const u32* __restrict__ cnt, float4* __restrict__ cbs_g,
    float4* __restrict__ obs_g, u64* __restrict__ kmask_g,
    const float4* __restrict__ P4f, float4* __restrict__ G4f){
#pragma clang fp contract(off)
  __shared__ __align__(16) u64 keys[CANDCAP];      // 8 KB (rank path only)
  const int u   = blockIdx.x;
  const int tid = threadIdx.x;
  if (u < 32){
    // ---- rank + decode ----
    const int img = u >> 2;
    const int sub = u & 3;
    const int M = min((int)cnt[img], CANDCAP);
    #pragma unroll
    for (int k = 0; k < 4; k++){
      int s = k*256 + tid;
      keys[s] = (s < M) ? cand[(long)img*CANDCAP + s] : 0ull;
    }
    __syncthreads();
    const int slot = sub*256 + tid;
    u64 k0 = keys[slot];
    int r0 = 0;
    const ulonglong2* kv = (const ulonglong2*)keys;
    for (int j = 0; j < CANDCAP/2; j++){              // wave-uniform b128 broadcast
      ulonglong2 kk = kv[j];
      r0 += (kk.x > k0) + (kk.y > k0);
    }
    if ((k0 >> 32) != 0ull && r0 < KC){
      u32 idxn = 0xFFFFFFFFu - (u32)(k0 & 0xFFFFFFFFull);
      const float* p = preds + ((long)img*NCAND + idxn)*PD;
      float cx = p[0], cy = p[1], w = p[2], h = p[3];
      float hw = w*0.5f, hh = h*0.5f;                 // exact
      float X1 = cx-hw, Y1 = cy-hh, X2 = cx+hw, Y2 = cy+hh;
      float off = (float)clsArr[(long)img*NCAND + idxn] * 4096.0f;  // exact
      obs_g[(long)img*KC + r0] = make_float4(X1, Y1, X2, Y2);
      cbs_g[(long)img*KC + r0] = make_float4(X1+off, Y1+off, X2+off, Y2+off);
      atomicOr(&kmask_g[img*8 + (r0 >> 6)], 1ull << (r0 & 63));
    }
    return;
  }
  // ---- reduce partial slabs into final G (L2-L4 region) ----
  const int N2 = P2_SLAB/4;   // 294912 f4
  const int N3 = P3_SLAB/4;   // 73728  f4
  const int N4 = P4_SLAB/4;   // 18432  f4
  int t = (u - 32)*256 + tid;
  if (t < N2){
    float4 a = P4f[t];
    float4 b = P4f[N2 + t];
    float4 r = make_float4(a.x+b.x, a.y+b.y, a.z+b.z, a.w+b.w);
    G4f[G2_OFF/4 + t] = r;
  } else if (t < N2 + N3){
    int w = t - N2;
    const float4* base = P4f + P3_BASE/4 + w;
    float4 r = base[0];
    #pragma unroll
    for (int s = 1; s < 4; s++){
      float4 b = base[(long)s*N3];
      r.x += b.x; r.y += b.y; r.z += b.z; r.w += b.w;
    }
    G4f[G3_OFF/4 + w] = r;
  } else if (t < N2 + N3 + N4){
    int w = t - N2 - N3;
    const float4* base = P4f + P4_BASE/4 + w;
    float4 r = base[0];
    #pragma unroll
    for (int s = 1; s < 8; s++){
      float4 b = base[(long)s*N4];
      r.x += b.x; r.y += b.y; r.z += b.z; r.w += b.w;
    }
    G4f[G4_OFF/4 + w] = r;
  }
}

// ---------------- K4b: IOU suppression matrix, 64 rows x 512 cols per block ----
__global__ __launch_bounds__(512) void k_iou(const float4* __restrict__ cbs_g,
    const u64* __restrict__ kmask_g, u64* __restrict__ lrows_g){
#pragma clang fp contract(off)
  __shared__ __align__(16) float4 cbsL[8*65];      // stride-65 swizzle: conflict-free
  const int img = blockIdx.x >> 3;
  const int ch  = blockIdx.x & 7;
  const int tid = threadIdx.x;
  if (tid < KC){
    u64 km = kmask_g[img*8 + (tid >> 6)];
    bool f = (km >> (tid & 63)) & 1ull;
    float4 v = f ? cbs_g[(long)img*KC + tid]
                 : make_float4(-4e8f, -4e8f, -4e8f, -4e8f);  // zero-area -> iou 0
    cbsL[(tid >> 6)*65 + (tid & 63)] = v;
  }
  __syncthreads();
  const int row = ch*64 + (tid >> 3);
  const int w   = tid & 7;
  float4 bi = cbsL[(row >> 6)*65 + (row & 63)];
  float areai = (bi.z - bi.x)*(bi.w - bi.y);
  u64 bits = 0ull;
  const int jbase = w*64;
  for (int b = 0; b < 64; b++){
    int j = jbase + b;
    if (j > row){
      float4 bj = cbsL[w*65 + b];
      float areaj = (bj.z - bj.x)*(bj.w - bj.y);
      float ltx = fmaxf(bi.x, bj.x), lty = fmaxf(bi.y, bj.y);
      float rbx = fminf(bi.z, bj.z), rby = fminf(bi.w, bj.w);
      float ww = fmaxf(rbx - ltx, 0.f);
      float hh = fmaxf(rby - lty, 0.f);
      float inter = ww*hh;
      float iou = inter / (areai + areaj - inter + 1e-7f);  // exact ref op order
      if (iou > 0.45f) bits |= (1ull << b);
    }
  }
  lrows_g[((long)img*KC + row)*8 + w] = bits;      // coalesced 8B stores
}

// ---------------- K4c: greedy suppression (serial core) + compact ----------------
__global__ __launch_bounds__(512) void k_greedy(const u64* __restrict__ lrows_g,
    const u64* __restrict__ kmask_g, const float4* __restrict__ obs_g,
    float* __restrict__ selbox, u32* __restrict__ selcnt){
  __shared__ __align__(16) u64 lrows[KC*8];        // 32 KB
  __shared__ u64 keepw[8];
  const int img = blockIdx.x;
  const int tid = threadIdx.x;
  const ulonglong2* src = (const ulonglong2*)(lrows_g + (long)img*KC*8);
  ulonglong2* dst = (ulonglong2*)lrows;
  #pragma unroll
  for (int k = 0; k < 4; k++) dst[k*512 + tid] = src[k*512 + tid];
  __syncthreads();
  if (tid < 64){
    const int lane = tid;
    const int w = lane & 7;
    u64 kw_own = kmask_g[img*8 + w];
    for (int b = 0; b < 8; b++){
      u64 kwb = shfl_u64(kw_own, b);
      for (int g = 0; g < 8; g++){
        u64 rdec[8], rown[8];
        #pragma unroll
        for (int k = 0; k < 8; k++){
          int i = b*64 + g*8 + k;
          rdec[k] = lrows[i*8 + b];
          rown[k] = lrows[i*8 + w];
        }
        #pragma unroll
        for (int k = 0; k < 8; k++){
          int il = g*8 + k;
          if ((kwb >> il) & 1ull){
            kwb    &= ~rdec[k];
            kw_own &= ~rown[k];
          }
        }
      }
    }
    if (lane < 8) keepw[lane] = kw_own;
  }
  __syncthreads();
  {
    u64 kk[8];
    #pragma unroll
    for (int w = 0; w < 8; w++) kk[w] = keepw[w];
    const int s = tid;
    const int wi = s >> 6, bi = s & 63;
    bool kept = (kk[wi] >> bi) & 1ull;
    if (kept){
      int rank = 0;
      for (int w = 0; w < wi; w++) rank += __popcll(kk[w]);
      rank += __popcll(bi ? (kk[wi] & ((1ull << bi) - 1ull)) : 0ull);
      if (rank < MAXDET){
        float4 ob = obs_g[(long)img*KC + s];
        float* sb = selbox + ((long)img*MAXDET + rank)*4;
        sb[0]=ob.x; sb[1]=ob.y; sb[2]=ob.z; sb[3]=ob.w;
      }
    }
    if (tid == 0){
      int tot = 0;
      #pragma unroll
      for (int w = 0; w < 8; w++) tot += __popcll(kk[w]);
      selcnt[img] = (u32)min(tot, MAXDET);
    }
  }
}

// ---------------- K6: fused ROI-gather + bias + leaky + layer2 + assembly ----------------
__device__ __forceinline__ void roi_level(const float* __restrict__ g,
    int Hl, int Wl, float scale, float x1, float y1, float x2, float y2,
    int lane, float& h){
  float bx1=x1*scale, by1=y1*scale, bx2=x2*scale, by2=y2*scale;
  float rw=fmaxf(bx2-bx1,1.f), rh=fmaxf(by2-by1,1.f);
  float ys[2]={by1+rh*0.25f, by1+rh*0.75f};
  float xs[2]={bx1+rw*0.25f, bx1+rw*0.75f};
  #pragma unroll
  for (int pt = 0; pt < 4; pt++){
    float y=ys[pt>>1], x=xs[pt&1];
    if ((y>-1.f)&&(y<(float)Hl)&&(x>-1.f)&&(x<(float)Wl)){   // wave-uniform branch
      float yc=fmaxf(y,0.f), xc=fmaxf(x,0.f);
      int y0=(int)fminf(floorf(yc),(float)(Hl-1));
      int x0=(int)fminf(floorf(xc),(float)(Wl-1));
      int y1i=min(y0+1,Hl-1), x1i=min(x0+1,Wl-1);
      float ly=yc-(float)y0, lx=xc-(float)x0;
      float hy=1.f-ly, hx=1.f-lx;
      h += (hy*hx*0.25f)*g[(long)(y0*Wl+x0)*64+lane];
      h += (hy*lx*0.25f)*g[(long)(y0*Wl+x1i)*64+lane];
      h += (ly*hx*0.25f)*g[(long)(y1i*Wl+x0)*64+lane];
      h += (ly*lx*0.25f)*g[(long)(y1i*Wl+x1i)*64+lane];
    }
  }
}

__global__ __launch_bounds__(256) void k_roi_mlp(const float* __restrict__ G,
    const float* __restrict__ selbox, const u32* __restrict__ selcnt,
    const float* __restrict__ b1, const float* __restrict__ W2,
    const float* __restrict__ b2, float* __restrict__ out){
  const int img  = blockIdx.y;
  const int wave = threadIdx.x >> 6;
  const int lane = threadIdx.x & 63;
  const int slot = blockIdx.x*4 + wave;
  if (slot >= MAXDET) return;
  float* o = out + ((long)img*MAXDET + slot)*68;
  if (slot >= (int)selcnt[img]){
    o[4+lane] = 0.f;
    if (lane < 4) o[lane] = 0.f;
    return;
  }
  const float* sb = selbox + ((long)img*MAXDET + slot)*4;
  float x1 = sb[0], y1 = sb[1], x2 = sb[2], y2 = sb[3];
  const float* Gi1 = G +          (long)img*9216*64;
  const float* Gi2 = G + G2_OFF + (long)img*2304*64;
  const float* Gi3 = G + G3_OFF + (long)img*576*64;
  const float* Gi4 = G + G4_OFF + (long)img*144*64;
  float h = 0.f;
  roi_level(Gi1, 96, 96, 0.125f,    x1,y1,x2,y2, lane, h);
  roi_level(Gi2, 48, 48, 0.0625f,   x1,y1,x2,y2, lane, h);
  roi_level(Gi3, 24, 24, 0.03125f,  x1,y1,x2,y2, lane, h);
  roi_level(Gi4, 12, 12, 0.015625f, x1,y1,x2,y2, lane, h);
  float h1 = leaky(h + b1[lane]);
  float c = 0.f;
  #pragma unroll 8
  for (int k = 0; k < 64; k++){
    float hk = __shfl(h1, k, 64);
    c += hk * W2[k*64 + lane];
  }
  o[4+lane] = leaky(c + b2[lane]);
  if (lane < 4) o[lane] = sb[lane] / 768.0f;
}

// ---------------- workspace layout (bytes) ----------------
// 0        hist    u32[8][2048]        65536
// 65536    cnt     u32[8]              256 (padded)
// 65792    kmask   u64[8][8]           512
// 66304    thr     u32[8]              256
// 66560    selbox  f32[8][300][4]      38400
// 104960   selcnt  u32[8]              256
// 105216   sbits   u32[8][36720]       1175040
// 1280256  cls     i32[8][36720]       1175040
// 2455296  cand    u64[8][1024]        65536
// 2520832  cbs_g   f4[8][512]          65536
// 2586368  obs_g   f4[8][512]          65536
// 2651904  lrows_g u64[8][512][8]      262144
// 2914048  G       f32 level-major     25067520
// 27981568 P       f32 partials        16515072   -> total ~44.5 MB
#define WS_G 2914048
#define WS_P 27981568

extern "C" void kernel_launch(void* const* d_in, const int* in_sizes, int n_in,
                              void* d_out, int out_size, void* d_ws, size_t ws_size,
                              hipStream_t stream){
  const float* preds = (const float*)d_in[0];
  const float* f1 = (const float*)d_in[1];
  const float* f2 = (const float*)d_in[2];
  const float* f3 = (const float*)d_in[3];
  const float* f4 = (const float*)d_in[4];
  const float* W1 = (const float*)d_in[5];
  const float* b1 = (const float*)d_in[6];
  const float* W2 = (const float*)d_in[7];
  const float* b2 = (const float*)d_in[8];
  float* out = (float*)d_out;
  char* ws = (char*)d_ws;
  u32* hist    = (u32*)(ws + 0);
  u32* cnt     = (u32*)(ws + 65536);
  u64* kmask_g = (u64*)(ws + 65792);
  u32* thr     = (u32*)(ws + 66304);
  float* selb  = (float*)(ws + 66560);
  u32* selc    = (u32*)(ws + 104960);
  u32* sbits   = (u32*)(ws + 105216);
  int* clsA    = (int*)(ws + 1280256);
  u64* cand    = (u64*)(ws + 2455296);
  float4* cbs_g = (float4*)(ws + 2520832);
  float4* obs_g = (float4*)(ws + 2586368);
  u64* lrows_g  = (u64*)(ws + 2651904);
  float* G     = (float*)(ws + WS_G);
  float* P     = (float*)(ws + WS_P);

  hipMemsetAsync(ws, 0, 66304, stream);                 // hist + cnt + kmask

  // A: score (288 blocks/img) + proj even works (72/img)
  k_front_a<<<dim3(360, B_IMG), 128, 0, stream>>>(preds, sbits, clsA, hist,
                                                  f1, f2, f3, f4, W1, G, P);
  k_thresh<<<B_IMG, 64, 0, stream>>>(hist, thr);
  // B: gather (288 blocks/img) + proj odd works (72/img)
  k_front_b<<<dim3(360, B_IMG), 128, 0, stream>>>(sbits, thr, cnt, cand,
                                                  f1, f2, f3, f4, W1, G, P);
  // C: rank (32 blocks) + reduce (1512 blocks)
  k_mid<<<32 + 1512, 256, 0, stream>>>(preds, clsA, cand, cnt, cbs_g, obs_g,
                                       kmask_g, (const float4*)P, (float4*)G);
  k_iou<<<B_IMG*8, 512, 0, stream>>>(cbs_g, kmask_g, lrows_g);
  k_greedy<<<B_IMG, 512, 0, stream>>>(lrows_g, kmask_g, obs_g, selb, selc);
  k_roi_mlp<<<dim3(75, B_IMG), 256, 0, stream>>>(G, selb, selc, b1, W2, b2, out);
}

// Round 15
// 321.188 us; speedup vs baseline: 1.0442x; 1.0442x over previous
//
#include <hip/hip_runtime.h>
#include <cstdint>

#define B_IMG   8
#define NCAND   36720
#define PD      85
#define NCLS    80
#define KC      512
#define MAXDET  300
#define NBUCK   2048
#define CANDCAP 1024      // gathered count is ~512 + one-bucket (<~40): 1024 is safe

// G (fp32, level-major) float offsets: L1[8][9216][64] | L2[8][2304][64] | L3[8][576][64] | L4[8][144][64]
#define G2_OFF 4718592
#define G3_OFF 5898240
#define G4_OFF 6193152
#define G_TOT  6266880

// Partial-sum buffer P (float offsets within P)
#define P2_BASE 0
#define P2_SLAB 1179648
#define P3_BASE 2359296
#define P3_SLAB 294912
#define P4_BASE 3538944
#define P4_SLAB 73728

typedef unsigned int u32;
typedef unsigned long long u64;

__device__ __forceinline__ float leaky(float x){ return x >= 0.f ? x : 0.01f*x; }

__device__ __forceinline__ u64 shfl_u64(u64 v, int lane){
  int lo = __shfl((int)(u32)(v & 0xFFFFFFFFull), lane, 64);
  int hi = __shfl((int)(u32)(v >> 32), lane, 64);
  return ((u64)(u32)hi << 32) | (u64)(u32)lo;
}
__device__ __forceinline__ u64 shfl_xor_u64(u64 v, int mask){
  int lo = __shfl_xor((int)(u32)(v & 0xFFFFFFFFull), mask, 64);
  int hi = __shfl_xor((int)(u32)(v >> 32), mask, 64);
  return ((u64)(u32)hi << 32) | (u64)(u32)lo;
}

__device__ __forceinline__ void gld16(const void* g, void* l){
  __builtin_amdgcn_global_load_lds((const __attribute__((address_space(1))) void*)g,
                                   (__attribute__((address_space(3))) void*)l, 16, 0, 0);
}

// ================= proj work (R7 config: 128 thr, 16-ch chunks, 24KB LDS) =====
// R17: R13 proved splitting proj across two kernels dilutes occupancy
// (13.9%, 2x60us); R8 proved score+proj fusion itself is ~free. This round:
// ONE fused kernel carries score AND ALL 144 proj works at R7's config
// (full 1152 proj blocks -> R7 occupancy), gather back standalone.
__device__ __forceinline__ void stage_chunk(const float4* __restrict__ feat4,
    const float4* __restrict__ W14, long fbase, int hw4, int px04, int Woff,
    int c0, int tid, float4* FsD, float4* WsD){
  const int wb = tid & ~63;                      // wave-uniform LDS base
  #pragma unroll
  for (int k = 0; k < 4; k++){                   // Fs: 16c x 32 f4 = 512 slots
    int s = tid + k*128; int c = s >> 5, q = s & 31;
    int pq = px04 + q; if (pq >= hw4) pq = hw4 - 1;   // ragged tile clamp (stores guarded)
    gld16(feat4 + fbase + (long)(c0 + c)*hw4 + pq, FsD + k*128 + wb);
  }
  #pragma unroll
  for (int k = 0; k < 2; k++){                   // Ws: 16c x 16 f4 = 256 slots
    int s = tid + k*128; int c = s >> 4, q = s & 15;
    gld16(W14 + (long)(Woff + c0 + c)*16 + q, WsD + k*128 + wb);
  }
}

#define FMA_Q(S, W, A) \
  A.x = fmaf(S, W.x, A.x); A.y = fmaf(S, W.y, A.y); \
  A.z = fmaf(S, W.z, A.z); A.w = fmaf(S, W.w, A.w);

__device__ __forceinline__ void proj_work(int w, int img, int tid,
    const float* __restrict__ f1, const float* __restrict__ f2,
    const float* __restrict__ f3, const float* __restrict__ f4,
    const float* __restrict__ W1, float* __restrict__ G, float* __restrict__ P,
    float* smem){
  float4* Fs0 = (float4*)smem;            // 512 f4 (16c x 32)
  float4* Fs1 = Fs0 + 512;
  float4* Ws0 = Fs0 + 1024;               // 256 f4 (16c x 16)
  float4* Ws1 = Fs0 + 1280;               // total 1536 f4 = 24 KB
  const float* feat; int C, HW, Woff, tile, split; long pbase; bool multi;
  if (w < 16)      { feat=f4; C=1024; HW=144;  Woff=896; tile=w>>3;      split=w&7;
                     pbase=P4_BASE + (long)split*P4_SLAB; multi=true;  }
  else if (w < 36) { feat=f3; C=512;  HW=576;  Woff=384; tile=(w-16)>>2; split=(w-16)&3;
                     pbase=P3_BASE + (long)split*P3_SLAB; multi=true;  }
  else if (w < 72) { feat=f2; C=256;  HW=2304; Woff=128; tile=(w-36)>>1; split=(w-36)&1;
                     pbase=P2_BASE + (long)split*P2_SLAB; multi=true;  }
  else             { feat=f1; C=128;  HW=9216; Woff=0;   tile=w-72;      split=0;
                     pbase=0; multi=false; }
  const int px0  = tile*128;
  const int hw4  = HW >> 2;
  const int px04 = px0 >> 2;
  const int jg   = tid & 7;         // j = jg*8 + jj (lane-fast axis)
  const int pg   = tid >> 3;        // px = px0 + pg*8 + p, pg=0..15
  const int c0b  = split*128;
  const float4* feat4 = (const float4*)feat;
  const float4* W14   = (const float4*)W1;
  const long fbase = (long)img*C*hw4;
  float4 z = make_float4(0.f,0.f,0.f,0.f);
  float4 aA0=z,aA1=z,aA2=z,aA3=z,aA4=z,aA5=z,aA6=z,aA7=z;  // j jg*8..+3
  float4 aB0=z,aB1=z,aB2=z,aB3=z,aB4=z,aB5=z,aB6=z,aB7=z;  // j jg*8+4..+7

  stage_chunk(feat4, W14, fbase, hw4, px04, Woff, c0b, tid, Fs0, Ws0);
  __syncthreads();                               // drains vmcnt: buf0 ready
  for (int ch = 0; ch < 8; ch++){
    if (ch < 7)                                  // issue next chunk into buf^1
      stage_chunk(feat4, W14, fbase, hw4, px04, Woff, c0b + (ch+1)*16, tid,
                  (ch & 1) ? Fs0 : Fs1, (ch & 1) ? Ws0 : Ws1);
    const float4* fsb = (ch & 1) ? Fs1 : Fs0;
    const float4* wsb = (ch & 1) ? Ws1 : Ws0;
    #pragma unroll 4
    for (int c = 0; c < 16; c++){
      float4 fa = fsb[c*32 + pg*2];        // px p=0..3   (8-lane broadcast)
      float4 fb = fsb[c*32 + pg*2 + 1];    // px p=4..7
      float4 wa = wsb[c*16 + jg*2];        // j jj=0..3   (2-way aliased: free)
      float4 wc = wsb[c*16 + jg*2 + 1];    // j jj=4..7
      FMA_Q(fa.x, wa, aA0) FMA_Q(fa.y, wa, aA1) FMA_Q(fa.z, wa, aA2) FMA_Q(fa.w, wa, aA3)
      FMA_Q(fb.x, wa, aA4) FMA_Q(fb.y, wa, aA5) FMA_Q(fb.z, wa, aA6) FMA_Q(fb.w, wa, aA7)
      FMA_Q(fa.x, wc, aB0) FMA_Q(fa.y, wc, aB1) FMA_Q(fa.z, wc, aB2) FMA_Q(fa.w, wc, aB3)
      FMA_Q(fb.x, wc, aB4) FMA_Q(fb.y, wc, aB5) FMA_Q(fb.z, wc, aB6) FMA_Q(fb.w, wc, aB7)
    }
    __syncthreads();                             // next-chunk loads drained + compute done
  }
  float* outb = multi ? (P + pbase + (long)img*HW*64)
                      : (G + (long)img*HW*64);           // L1 region starts at G+0
  const int pxa = px0 + pg*8;
#define STOREQ(A, B, PP) do { int gp = pxa + (PP); if (gp < HW){ \
    *(float4*)(outb + (long)gp*64 + jg*8) = A; \
    *(float4*)(outb + (long)gp*64 + jg*8 + 4) = B; } } while(0)
  STOREQ(aA0, aB0, 0); STOREQ(aA1, aB1, 1); STOREQ(aA2, aB2, 2); STOREQ(aA3, aB3, 3);
  STOREQ(aA4, aB4, 4); STOREQ(aA5, aB5, 5); STOREQ(aA6, aB6, 6); STOREQ(aA7, aB7, 7);
#undef STOREQ
}

// ---------------- KA: fused score (blocks 0..287) + ALL proj works (288..431) ----
__global__ __launch_bounds__(128) void k_front(const float* __restrict__ preds,
    u32* __restrict__ sbits, int* __restrict__ clsArr, u32* __restrict__ hist,
    const float* __restrict__ f1, const float* __restrict__ f2,
    const float* __restrict__ f3, const float* __restrict__ f4,
    const float* __restrict__ W1, float* __restrict__ G, float* __restrict__ P){
  __shared__ __align__(16) float smem[6144];     // 24 KB union
  const int img = blockIdx.y;
  const int u   = blockIdx.x;
  const int tid = threadIdx.x;

  if (u < 288){
    // ---- score (2 waves/block) ----
    u32*   sl_lane = (u32*)smem;          // [2][64]
    float* sl_obj  = smem + 128;
    u32*   sl_res  = (u32*)(smem + 256);
    u32*   sl_cls  = (u32*)(smem + 384);
    const int wv   = tid >> 6;
    const int lane = tid & 63;
    const int base = (u*2 + wv)*64;
    const int ci   = base + lane;
    const bool inb = ci < NCAND;
    float obj = 0.f;
    if (inb) obj = preds[((long)img*NCAND + ci)*PD + 4];
    const bool pass = obj > 0.596f;
    u64 mask = __ballot(pass);
    int cnt  = __popcll(mask);
    int rank = __popcll(mask & ((1ull << lane) - 1ull));
    if (pass){ sl_lane[wv*64 + rank] = (u32)lane; sl_obj[wv*64 + rank] = obj; }
    const int q = lane & 3;
    for (int r0 = 0; r0 < cnt; r0 += 16){
      int idx = r0 + (lane >> 2);
      if (idx < cnt){
        u32 sl = sl_lane[wv*64 + idx];
        float obj2 = sl_obj[wv*64 + idx];
        const float* p2 = preds + ((long)img*NCAND + base + (int)sl)*PD + 5 + q;
        u64 best = 0ull;
        #pragma unroll
        for (int k = 0; k < 20; k++){
          float v = p2[4*k] * obj2;                       // exact ref: cls*obj
          u64 key = ((u64)__float_as_uint(v) << 32) | (u64)(~(u32)(q + 4*k));
          if (key > best) best = key;                     // first max wins
        }
        u64 o1 = shfl_xor_u64(best, 1); if (o1 > best) best = o1;
        u64 o2 = shfl_xor_u64(best, 2); if (o2 > best) best = o2;
        if (q == 0){
          u32 bits = (u32)(best >> 32);
          sl_res[wv*64 + sl] = (__uint_as_float(bits) > 0.596f) ? bits : 0u;
          sl_cls[wv*64 + sl] = ~(u32)(best & 0xFFFFFFFFull);
        }
      }
    }
    if (inb){
      u32 out = pass ? sl_res[wv*64 + lane] : 0u;
      sbits[(long)img*NCAND + ci] = out;
      if (pass) clsArr[(long)img*NCAND + ci] = (int)sl_cls[wv*64 + lane];
      if (out) atomicAdd(&hist[img*NBUCK + ((out - 0x3F000000u) >> 12)], 1u);
    }
    return;
  }
  proj_work(u - 288, img, tid, f1, f2, f3, f4, W1, G, P, smem);
}

// ---------------- K2: per-image bit-threshold covering top-512 ----------------
__global__ __launch_bounds__(64) void k_thresh(const u32* __restrict__ hist,
                                               u32* __restrict__ thr){
  const int img = blockIdx.x;
  const int lane = threadIdx.x;
  const u32* h = hist + img*NBUCK;
  u32 acc = 0; u32 result = 0x3F000000u; bool found = false;
  for (int g = NBUCK/64 - 1; g >= 0 && !found; g--){
    u32 v = h[g*64 + lane];
    u32 s = v;
    #pragma unroll
    for (int off = 1; off < 64; off <<= 1){
      u32 t = __shfl_down(s, off, 64);
      s += (lane + off < 64) ? t : 0u;
    }
    u64 mask = __ballot(acc + s >= KC);
    if (mask){
      int hl = 63 - __clzll(mask);
      result = 0x3F000000u + ((u32)(g*64 + hl) << 12);
      found = true;
    }
    acc += __shfl(s, 0, 64);
  }
  if (lane == 0) thr[img] = result;
}

// ---------------- K3: gather candidates >= threshold as sortable keys ----------------
__global__ __launch_bounds__(256) void k_gather(const u32* __restrict__ sbits,
    const u32* __restrict__ thr, u32* __restrict__ cnt, u64* __restrict__ cand){
  int img = blockIdx.y;
  int n = blockIdx.x*256 + threadIdx.x;
  if (n >= NCAND) return;
  u32 bits = sbits[(long)img*NCAND + n];
  if (bits && bits >= thr[img]){
    u32 pos = atomicAdd(&cnt[img], 1u);
    if (pos < CANDCAP)
      cand[(long)img*CANDCAP + pos] = ((u64)bits << 32) | (u64)(0xFFFFFFFFu - (u32)n);
  }
}

// ---------------- K_MID: fused rank (blocks 0..31) + split-K reduce (32..1543) ----
__global__ __launch_bounds__(256) void k_mid(const float* __restrict__ preds,
    const int* __restrict__ clsArr, const u64* __restrict__ cand,
    const u32* __restrict__ cnt, float4* __restrict__ cbs_g,
    float4* __restrict__ obs_g, u64* __restrict__ kmask_g,
    const float4* __restrict__ P4f, float4* __restrict__ G4f){
#pragma clang fp contract(off)
  __shared__ __align__(16) u64 keys[CANDCAP];      // 8 KB (rank path only)
  const int u   = blockIdx.x;
  const int tid = threadIdx.x;
  if (u < 32){
    // ---- rank + decode ----
    const int img = u >> 2;
    const int sub = u & 3;
    const int M = min((int)cnt[img], CANDCAP);
    #pragma unroll
    for (int k = 0; k < 4; k++){
      int s = k*256 + tid;
      keys[s] = (s < M) ? cand[(long)img*CANDCAP + s] : 0ull;
    }
    __syncthreads();
    const int slot = sub*256 + tid;
    u64 k0 = keys[slot];
    int r0 = 0;
    const ulonglong2* kv = (const ulonglong2*)keys;
    for (int j = 0; j < CANDCAP/2; j++){              // wave-uniform b128 broadcast
      ulonglong2 kk = kv[j];
      r0 += (kk.x > k0) + (kk.y > k0);
    }
    if ((k0 >> 32) != 0ull && r0 < KC){
      u32 idxn = 0xFFFFFFFFu - (u32)(k0 & 0xFFFFFFFFull);
      const float* p = preds + ((long)img*NCAND + idxn)*PD;
      float cx = p[0], cy = p[1], w = p[2], h = p[3];
      float hw = w*0.5f, hh = h*0.5f;                 // exact
      float X1 = cx-hw, Y1 = cy-hh, X2 = cx+hw, Y2 = cy+hh;
      float off = (float)clsArr[(long)img*NCAND + idxn] * 4096.0f;  // exact
      obs_g[(long)img*KC + r0] = make_float4(X1, Y1, X2, Y2);
      cbs_g[(long)img*KC + r0] = make_float4(X1+off, Y1+off, X2+off, Y2+off);
      atomicOr(&kmask_g[img*8 + (r0 >> 6)], 1ull << (r0 & 63));
    }
    return;
  }
  // ---- reduce partial slabs into final G (L2-L4 region) ----
  const int N2 = P2_SLAB/4;   // 294912 f4
  const int N3 = P3_SLAB/4;   // 73728  f4
  const int N4 = P4_SLAB/4;   // 18432  f4
  int t = (u - 32)*256 + tid;
  if (t < N2){
    float4 a = P4f[t];
    float4 b = P4f[N2 + t];
    float4 r = make_float4(a.x+b.x, a.y+b.y, a.z+b.z, a.w+b.w);
    G4f[G2_OFF/4 + t] = r;
  } else if (t < N2 + N3){
    int w = t - N2;
    const float4* base = P4f + P3_BASE/4 + w;
    float4 r = base[0];
    #pragma unroll
    for (int s = 1; s < 4; s++){
      float4 b = base[(long)s*N3];
      r.x += b.x; r.y += b.y; r.z += b.z; r.w += b.w;
    }
    G4f[G3_OFF/4 + w] = r;
  } else if (t < N2 + N3 + N4){
    int w = t - N2 - N3;
    const float4* base = P4f + P4_BASE/4 + w;
    float4 r = base[0];
    #pragma unroll
    for (int s = 1; s < 8; s++){
      float4 b = base[(long)s*N4];
      r.x += b.x; r.y += b.y; r.z += b.z; r.w += b.w;
    }
    G4f[G4_OFF/4 + w] = r;
  }
}

// ---------------- K4b: IOU suppression matrix, 64 rows x 512 cols per block ----
__global__ __launch_bounds__(512) void k_iou(const float4* __restrict__ cbs_g,
    const u64* __restrict__ kmask_g, u64* __restrict__ lrows_g){
#pragma clang fp contract(off)
  __shared__ __align__(16) float4 cbsL[8*65];      // stride-65 swizzle: conflict-free
  const int img = blockIdx.x >> 3;
  const int ch  = blockIdx.x & 7;
  const int tid = threadIdx.x;
  if (tid < KC){
    u64 km = kmask_g[img*8 + (tid >> 6)];
    bool f = (km >> (tid & 63)) & 1ull;
    float4 v = f ? cbs_g[(long)img*KC + tid]
                 : make_float4(-4e8f, -4e8f, -4e8f, -4e8f);  // zero-area -> iou 0
    cbsL[(tid >> 6)*65 + (tid & 63)] = v;
  }
  __syncthreads();
  const int row = ch*64 + (tid >> 3);
  const int w   = tid & 7;
  float4 bi = cbsL[(row >> 6)*65 + (row & 63)];
  float areai = (bi.z - bi.x)*(bi.w - bi.y);
  u64 bits = 0ull;
  const int jbase = w*64;
  for (int b = 0; b < 64; b++){
    int j = jbase + b;
    if (j > row){
      float4 bj = cbsL[w*65 + b];
      float areaj = (bj.z - bj.x)*(bj.w - bj.y);
      float ltx = fmaxf(bi.x, bj.x), lty = fmaxf(bi.y, bj.y);
      float rbx = fminf(bi.z, bj.z), rby = fminf(bi.w, bj.w);
      float ww = fmaxf(rbx - ltx, 0.f);
      float hh = fmaxf(rby - lty, 0.f);
      float inter = ww*hh;
      float iou = inter / (areai + areaj - inter + 1e-7f);  // exact ref op order
      if (iou > 0.45f) bits |= (1ull << b);
    }
  }
  lrows_g[((long)img*KC + row)*8 + w] = bits;      // coalesced 8B stores
}

// ---------------- K4c: greedy suppression (serial core) + compact ----------------
__global__ __launch_bounds__(512) void k_greedy(const u64* __restrict__ lrows_g,
    const u64* __restrict__ kmask_g, const float4* __restrict__ obs_g,
    float* __restrict__ selbox, u32* __restrict__ selcnt){
  __shared__ __align__(16) u64 lrows[KC*8];        // 32 KB
  __shared__ u64 keepw[8];
  const int img = blockIdx.x;
  const int tid = threadIdx.x;
  const ulonglong2* src = (const ulonglong2*)(lrows_g + (long)img*KC*8);
  ulonglong2* dst = (ulonglong2*)lrows;
  #pragma unroll
  for (int k = 0; k < 4; k++) dst[k*512 + tid] = src[k*512 + tid];
  __syncthreads();
  if (tid < 64){
    const int lane = tid;
    const int w = lane & 7;
    u64 kw_own = kmask_g[img*8 + w];
    for (int b = 0; b < 8; b++){
      u64 kwb = shfl_u64(kw_own, b);
      for (int g = 0; g < 8; g++){
        u64 rdec[8], rown[8];
        #pragma unroll
        for (int k = 0; k < 8; k++){
          int i = b*64 + g*8 + k;
          rdec[k] = lrows[i*8 + b];
          rown[k] = lrows[i*8 + w];
        }
        #pragma unroll
        for (int k = 0; k < 8; k++){
          int il = g*8 + k;
          if ((kwb >> il) & 1ull){
            kwb    &= ~rdec[k];
            kw_own &= ~rown[k];
          }
        }
      }
    }
    if (lane < 8) keepw[lane] = kw_own;
  }
  __syncthreads();
  {
    u64 kk[8];
    #pragma unroll
    for (int w = 0; w < 8; w++) kk[w] = keepw[w];
    const int s = tid;
    const int wi = s >> 6, bi = s & 63;
    bool kept = (kk[wi] >> bi) & 1ull;
    if (kept){
      int rank = 0;
      for (int w = 0; w < wi; w++) rank += __popcll(kk[w]);
      rank += __popcll(bi ? (kk[wi] & ((1ull << bi) - 1ull)) : 0ull);
      if (rank < MAXDET){
        float4 ob = obs_g[(long)img*KC + s];
        float* sb = selbox + ((long)img*MAXDET + rank)*4;
        sb[0]=ob.x; sb[1]=ob.y; sb[2]=ob.z; sb[3]=ob.w;
      }
    }
    if (tid == 0){
      int tot = 0;
      #pragma unroll
      for (int w = 0; w < 8; w++) tot += __popcll(kk[w]);
      selcnt[img] = (u32)min(tot, MAXDET);
    }
  }
}

// ---------------- K6: fused ROI-gather + bias + leaky + layer2 + assembly ----------------
__device__ __forceinline__ void roi_level(const float* __restrict__ g,
    int Hl, int Wl, float scale, float x1, float y1, float x2, float y2,
    int lane, float& h){
  float bx1=x1*scale, by1=y1*scale, bx2=x2*scale, by2=y2*scale;
  float rw=fmaxf(bx2-bx1,1.f), rh=fmaxf(by2-by1,1.f);
  float ys[2]={by1+rh*0.25f, by1+rh*0.75f};
  float xs[2]={bx1+rw*0.25f, bx1+rw*0.75f};
  #pragma unroll
  for (int pt = 0; pt < 4; pt++){
    float y=ys[pt>>1], x=xs[pt&1];
    if ((y>-1.f)&&(y<(float)Hl)&&(x>-1.f)&&(x<(float)Wl)){   // wave-uniform branch
      float yc=fmaxf(y,0.f), xc=fmaxf(x,0.f);
      int y0=(int)fminf(floorf(yc),(float)(Hl-1));
      int x0=(int)fminf(floorf(xc),(float)(Wl-1));
      int y1i=min(y0+1,Hl-1), x1i=min(x0+1,Wl-1);
      float ly=yc-(float)y0, lx=xc-(float)x0;
      float hy=1.f-ly, hx=1.f-lx;
      h += (hy*hx*0.25f)*g[(long)(y0*Wl+x0)*64+lane];
      h += (hy*lx*0.25f)*g[(long)(y0*Wl+x1i)*64+lane];
      h += (ly*hx*0.25f)*g[(long)(y1i*Wl+x0)*64+lane];
      h += (ly*lx*0.25f)*g[(long)(y1i*Wl+x1i)*64+lane];
    }
  }
}

__global__ __launch_bounds__(256) void k_roi_mlp(const float* __restrict__ G,
    const float* __restrict__ selbox, const u32* __restrict__ selcnt,
    const float* __restrict__ b1, const float* __restrict__ W2,
    const float* __restrict__ b2, float* __restrict__ out){
  const int img  = blockIdx.y;
  const int wave = threadIdx.x >> 6;
  const int lane = threadIdx.x & 63;
  const int slot = blockIdx.x*4 + wave;
  if (slot >= MAXDET) return;
  float* o = out + ((long)img*MAXDET + slot)*68;
  if (slot >= (int)selcnt[img]){
    o[4+lane] = 0.f;
    if (lane < 4) o[lane] = 0.f;
    return;
  }
  const float* sb = selbox + ((long)img*MAXDET + slot)*4;
  float x1 = sb[0], y1 = sb[1], x2 = sb[2], y2 = sb[3];
  const float* Gi1 = G +          (long)img*9216*64;
  const float* Gi2 = G + G2_OFF + (long)img*2304*64;
  const float* Gi3 = G + G3_OFF + (long)img*576*64;
  const float* Gi4 = G + G4_OFF + (long)img*144*64;
  float h = 0.f;
  roi_level(Gi1, 96, 96, 0.125f,    x1,y1,x2,y2, lane, h);
  roi_level(Gi2, 48, 48, 0.0625f,   x1,y1,x2,y2, lane, h);
  roi_level(Gi3, 24, 24, 0.03125f,  x1,y1,x2,y2, lane, h);
  roi_level(Gi4, 12, 12, 0.015625f, x1,y1,x2,y2, lane, h);
  float h1 = leaky(h + b1[lane]);
  float c = 0.f;
  #pragma unroll 8
  for (int k = 0; k < 64; k++){
    float hk = __shfl(h1, k, 64);
    c += hk * W2[k*64 + lane];
  }
  o[4+lane] = leaky(c + b2[lane]);
  if (lane < 4) o[lane] = sb[lane] / 768.0f;
}

// ---------------- workspace layout (bytes) ----------------
// 0        hist    u32[8][2048]        65536
// 65536    cnt     u32[8]              256 (padded)
// 65792    kmask   u64[8][8]           512
// 66304    thr     u32[8]              256
// 66560    selbox  f32[8][300][4]      38400
// 104960   selcnt  u32[8]              256
// 105216   sbits   u32[8][36720]       1175040
// 1280256  cls     i32[8][36720]       1175040
// 2455296  cand    u64[8][1024]        65536
// 2520832  cbs_g   f4[8][512]          65536
// 2586368  obs_g   f4[8][512]          65536
// 2651904  lrows_g u64[8][512][8]      262144
// 2914048  G       f32 level-major     25067520
// 27981568 P       f32 partials        16515072   -> total ~44.5 MB
#define WS_G 2914048
#define WS_P 27981568

extern "C" void kernel_launch(void* const* d_in, const int* in_sizes, int n_in,
                              void* d_out, int out_size, void* d_ws, size_t ws_size,
                              hipStream_t stream){
  const float* preds = (const float*)d_in[0];
  const float* f1 = (const float*)d_in[1];
  const float* f2 = (const float*)d_in[2];
  const float* f3 = (const float*)d_in[3];
  const float* f4 = (const float*)d_in[4];
  const float* W1 = (const float*)d_in[5];
  const float* b1 = (const float*)d_in[6];
  const float* W2 = (const float*)d_in[7];
  const float* b2 = (const float*)d_in[8];
  float* out = (float*)d_out;
  char* ws = (char*)d_ws;
  u32* hist    = (u32*)(ws + 0);
  u32* cnt     = (u32*)(ws + 65536);
  u64* kmask_g = (u64*)(ws + 65792);
  u32* thr     = (u32*)(ws + 66304);
  float* selb  = (float*)(ws + 66560);
  u32* selc    = (u32*)(ws + 104960);
  u32* sbits   = (u32*)(ws + 105216);
  int* clsA    = (int*)(ws + 1280256);
  u64* cand    = (u64*)(ws + 2455296);
  float4* cbs_g = (float4*)(ws + 2520832);
  float4* obs_g = (float4*)(ws + 2586368);
  u64* lrows_g  = (u64*)(ws + 2651904);
  float* G     = (float*)(ws + WS_G);
  float* P     = (float*)(ws + WS_P);

  hipMemsetAsync(ws, 0, 66304, stream);                 // hist + cnt + kmask

  // fused: score (288 blocks/img) + ALL proj works (144/img)
  k_front<<<dim3(432, B_IMG), 128, 0, stream>>>(preds, sbits, clsA, hist,
                                                f1, f2, f3, f4, W1, G, P);
  k_thresh<<<B_IMG, 64, 0, stream>>>(hist, thr);
  k_gather<<<dim3(144, B_IMG), 256, 0, stream>>>(sbits, thr, cnt, cand);
  // fused: rank (32 blocks) + reduce (1512 blocks)
  k_mid<<<32 + 1512, 256, 0, stream>>>(preds, clsA, cand, cnt, cbs_g, obs_g,
                                       kmask_g, (const float4*)P, (float4*)G);
  k_iou<<<B_IMG*8, 512, 0, stream>>>(cbs_g, kmask_g, lrows_g);
  k_greedy<<<B_IMG, 512, 0, stream>>>(lrows_g, kmask_g, obs_g, selb, selc);
  k_roi_mlp<<<dim3(75, B_IMG), 256, 0, stream>>>(G, selb, selc, b1, W2, b2, out);
}